// Round 4
// baseline (192.603 us; speedup 1.0000x reference)
//
#include <hip/hip_runtime.h>
#include <math.h>

using u16 = unsigned short;
typedef __attribute__((ext_vector_type(8))) __bf16 bf16x8;
typedef __attribute__((ext_vector_type(4))) float f32x4;
typedef __attribute__((ext_vector_type(4))) float f4v;
typedef __attribute__((ext_vector_type(8))) u16 u16x8;

__device__ __forceinline__ u16 f2bf(float f) {
  unsigned u = __float_as_uint(f);
  u += 0x7fffu + ((u >> 16) & 1u);   // round-to-nearest-even
  return (u16)(u >> 16);
}

__device__ __forceinline__ void gload16(const void* g, void* l) {
  __builtin_amdgcn_global_load_lds(
      (const __attribute__((address_space(1))) unsigned int*)g,
      (__attribute__((address_space(3))) unsigned int*)l, 16, 0, 0);
}

__device__ __forceinline__ f32x4 MF(bf16x8 a, bf16x8 b, f32x4 c) {
  return __builtin_amdgcn_mfma_f32_16x16x32_bf16(a, b, c, 0, 0, 0);
}

#define BARX() __builtin_amdgcn_s_barrier()
#define LGKM0() asm volatile("s_waitcnt lgkmcnt(0)" ::: "memory")
#define VMW4() asm volatile("s_waitcnt vmcnt(4)" ::: "memory")
#define VMW0() asm volatile("s_waitcnt vmcnt(0)" ::: "memory")

// ---------------------------------------------------------------- cast f32->bf16 (3 tensors)
__global__ __launch_bounds__(256) void cast3_f32_bf16(
    const float* __restrict__ p0, const float* __restrict__ p1,
    const float* __restrict__ p2, u16* __restrict__ out, size_t ostride) {
  int z = blockIdx.z;
  const float* in = (z == 0) ? p0 : (z == 1) ? p1 : p2;
  size_t i = ((size_t)blockIdx.x * 256 + threadIdx.x) * 8;
  f4v a = *reinterpret_cast<const f4v*>(in + i);
  f4v b = *reinterpret_cast<const f4v*>(in + i + 4);
  u16x8 r;
  r[0] = f2bf(a[0]); r[1] = f2bf(a[1]); r[2] = f2bf(a[2]); r[3] = f2bf(a[3]);
  r[4] = f2bf(b[0]); r[5] = f2bf(b[1]); r[6] = f2bf(b[2]); r[7] = f2bf(b[3]);
  *reinterpret_cast<u16x8*>(out + z * ostride + i) = r;
}

// ---------------------------------------------------------------- bf16 transpose
// in: [4][2048][1024]  -> out: [4][1024][2048]
__global__ __launch_bounds__(256) void transpose_bf16k(const u16* __restrict__ in,
                                                       u16* __restrict__ out) {
  __shared__ u16 t[64][65];
  int c0 = blockIdx.x * 64, r0 = blockIdx.y * 64;
  size_t zb = (size_t)blockIdx.z * 2048 * 1024;
  const u16* I = in + zb;
  u16* O = out + zb;
  int tx = threadIdx.x & 63, ty = threadIdx.x >> 6;
  #pragma unroll
  for (int i = 0; i < 64; i += 4)
    t[ty + i][tx] = I[(size_t)(r0 + ty + i) * 1024 + c0 + tx];
  __syncthreads();
  #pragma unroll
  for (int i = 0; i < 64; i += 4)
    O[(size_t)(c0 + ty + i) * 2048 + r0 + tx] = t[tx][ty + i];
}

// ================================================================ 256x256 8-phase GEMM
// C = alpha * A . B^T.  BM=BN=256, BK=64, 512 threads = 8 waves (2M x 4N),
// per-wave C: 128x64 (8 m-frags x 4 n-frags of 16x16).
// LDS 128 KiB: 2 buffers x (A 32KB + B 32KB); each tile half = 128 rows x 128B.
// XOR swizzle: 16B slot index ^= (row & 7); applied via pre-swizzled global src
// (linear global_load_lds dest) + swizzled ds_read address.
// Staging stream (strictly race-free): A-halves of tile t+1 at phases 0/1 (other
// buffer); B-halves of tile t+2 at phases 1/2 (current buffer, after all B reads
// of tile t completed at phase 0). vmcnt(4) once per K-tile at phase 3.
// MODE 0: stacked projection (A = [3*8192][1024]; weight slab + C ptr by bm>>5).
// MODE 1: causal QK^T, triangular-packed tiles, batched.
template<typename OutT, int MODE>
__global__ __launch_bounds__(512, 2) void gemm256(
    const u16* __restrict__ A, const u16* __restrict__ B, OutT* __restrict__ C,
    int K, int lda, int ldb, int ldc, size_t sA, size_t sB, size_t sC,
    float alpha, OutT* __restrict__ C1, OutT* __restrict__ C2) {
  int bm, bn, bz = 0, cm;
  const u16 *Ag, *Bg;
  OutT* Cg;
  if (MODE == 0) {                      // grid 384 = 96 m x 4 n, XCD-chunked
    int h = blockIdx.x;
    int l = (h & 7) * 48 + (h >> 3);
    bn = l & 3;
    bm = l >> 2;                        // 0..95 over stacked QKV rows
    int which = bm >> 5;
    cm = bm & 31;
    Ag = A + (size_t)bm * 256 * lda;
    Bg = B + (size_t)which * sB + (size_t)bn * 256 * ldb;
    Cg = (which == 0) ? C : (which == 1) ? C1 : C2;
  } else {                              // grid 144 = 4 batches x 36 tri tiles
    int h = blockIdx.x;
    int l = (h & 7) * 18 + (h >> 3);
    bz = l / 36;
    int tt = l % 36;
    bm = (int)((sqrtf(8.f * (float)tt + 1.f) - 1.f) * 0.5f);
    while ((bm + 1) * (bm + 2) / 2 <= tt) ++bm;
    while (bm * (bm + 1) / 2 > tt) --bm;
    bn = tt - bm * (bm + 1) / 2;
    cm = bm;
    Ag = A + sA * bz + (size_t)bm * 256 * lda;
    Bg = B + sB * bz + (size_t)bn * 256 * ldb;
    Cg = C + sC * bz;
  }

  __shared__ __align__(16) char sm[131072];

  const int tid = threadIdx.x;
  const int lane = tid & 63, wv = tid >> 6;     // wave 0..7
  const int wr = wv >> 2, wc = wv & 3;          // 2M x 4N wave grid
  const int fr = lane & 15, hi = lane >> 4, fr7 = lane & 7;
  const int l3 = lane >> 3;
  const int colsw = ((lane & 7) ^ l3) * 8;      // pre-swizzled global col (elems)
  const int lnx16 = lane * 16;

  // staging bases: wave wv stages chunks {wv, wv+8} of each 16KB half-tile
  const u16 *pA[2][2], *pB[2][2];
  int ldsA[2][2], ldsB[2][2];
  #pragma unroll
  for (int hh = 0; hh < 2; ++hh)
    #pragma unroll
    for (int j = 0; j < 2; ++j) {
      int row = hh * 128 + wv * 8 + j * 64 + l3;
      pA[hh][j] = Ag + (size_t)row * lda + colsw;
      pB[hh][j] = Bg + (size_t)row * ldb + colsw;
      ldsA[hh][j] = hh * 16384 + (wv + j * 8) * 1024 + lnx16;
      ldsB[hh][j] = 32768 + ldsA[hh][j];
    }

  // ds_read fragment addressing (swizzled)
  const int aBase = wr * 16384 + fr * 128;
  const int bBase = 32768 + (wc >> 1) * 16384 + ((wc & 1) * 64 + fr) * 128;
  const int sl0 = (hi ^ fr7) << 4;
  const int sl1 = ((4 + hi) ^ fr7) << 4;

#define RDA(buf, m, kk) (*(const bf16x8*)((buf) + aBase + (m) * 2048 + ((kk) ? sl1 : sl0)))
#define RDB(buf, n, kk) (*(const bf16x8*)((buf) + bBase + (n) * 2048 + ((kk) ? sl1 : sl0)))

  f32x4 acc[8][4] = {};
  const int nt = K >> 6;   // K-tiles of 64

  // ---- prologue: tile0 all 4 halves + tile1 B halves -> vmcnt(4)
  {
    char* b0 = sm;
    gload16(pA[0][0], b0 + ldsA[0][0]); gload16(pA[0][1], b0 + ldsA[0][1]);
    gload16(pA[1][0], b0 + ldsA[1][0]); gload16(pA[1][1], b0 + ldsA[1][1]);
    gload16(pB[0][0], b0 + ldsB[0][0]); gload16(pB[0][1], b0 + ldsB[0][1]);
    gload16(pB[1][0], b0 + ldsB[1][0]); gload16(pB[1][1], b0 + ldsB[1][1]);
    char* b1 = sm + 65536;
    gload16(pB[0][0] + 64, b1 + ldsB[0][0]); gload16(pB[0][1] + 64, b1 + ldsB[0][1]);
    gload16(pB[1][0] + 64, b1 + ldsB[1][0]); gload16(pB[1][1] + 64, b1 + ldsB[1][1]);
  }
  VMW4();
  BARX();

  for (int t = 0; t < nt; ++t) {
    const int cur = t & 1;
    const char* buf = sm + cur * 65536;
    char* nbuf = sm + (cur ^ 1) * 65536;
    char* cbuf = sm + cur * 65536;
    const bool st1 = (t + 1 < nt), st2 = (t + 2 < nt);
    bf16x8 bf0[4], bf1[4];
    bf16x8 a00, a01, a10, a11;

    // ---------- phase 0: read A m0,m1 + all B; stage A-h0(t+1); MFMA m0,m1
    a00 = RDA(buf, 0, 0); a01 = RDA(buf, 0, 1);
    a10 = RDA(buf, 1, 0); a11 = RDA(buf, 1, 1);
    #pragma unroll
    for (int n = 0; n < 4; ++n) { bf0[n] = RDB(buf, n, 0); bf1[n] = RDB(buf, n, 1); }
    if (st1) {
      gload16(pA[0][0] + (t + 1) * 64, nbuf + ldsA[0][0]);
      gload16(pA[0][1] + (t + 1) * 64, nbuf + ldsA[0][1]);
    }
    BARX(); LGKM0();
    __builtin_amdgcn_s_setprio(1);
    #pragma unroll
    for (int n = 0; n < 4; ++n) {
      acc[0][n] = MF(a00, bf0[n], acc[0][n]);
      acc[0][n] = MF(a01, bf1[n], acc[0][n]);
      acc[1][n] = MF(a10, bf0[n], acc[1][n]);
      acc[1][n] = MF(a11, bf1[n], acc[1][n]);
    }
    __builtin_amdgcn_s_setprio(0);
    BARX();

    // ---------- phase 1: read A m2,m3; stage A-h1(t+1), B-h0(t+2); MFMA m2,m3
    a00 = RDA(buf, 2, 0); a01 = RDA(buf, 2, 1);
    a10 = RDA(buf, 3, 0); a11 = RDA(buf, 3, 1);
    if (st1) {
      gload16(pA[1][0] + (t + 1) * 64, nbuf + ldsA[1][0]);
      gload16(pA[1][1] + (t + 1) * 64, nbuf + ldsA[1][1]);
    }
    if (st2) {
      gload16(pB[0][0] + (t + 2) * 64, cbuf + ldsB[0][0]);
      gload16(pB[0][1] + (t + 2) * 64, cbuf + ldsB[0][1]);
    }
    BARX(); LGKM0();
    __builtin_amdgcn_s_setprio(1);
    #pragma unroll
    for (int n = 0; n < 4; ++n) {
      acc[2][n] = MF(a00, bf0[n], acc[2][n]);
      acc[2][n] = MF(a01, bf1[n], acc[2][n]);
      acc[3][n] = MF(a10, bf0[n], acc[3][n]);
      acc[3][n] = MF(a11, bf1[n], acc[3][n]);
    }
    __builtin_amdgcn_s_setprio(0);
    BARX();

    // ---------- phase 2: read A m4,m5; stage B-h1(t+2); MFMA m4,m5
    a00 = RDA(buf, 4, 0); a01 = RDA(buf, 4, 1);
    a10 = RDA(buf, 5, 0); a11 = RDA(buf, 5, 1);
    if (st2) {
      gload16(pB[1][0] + (t + 2) * 64, cbuf + ldsB[1][0]);
      gload16(pB[1][1] + (t + 2) * 64, cbuf + ldsB[1][1]);
    }
    BARX(); LGKM0();
    __builtin_amdgcn_s_setprio(1);
    #pragma unroll
    for (int n = 0; n < 4; ++n) {
      acc[4][n] = MF(a00, bf0[n], acc[4][n]);
      acc[4][n] = MF(a01, bf1[n], acc[4][n]);
      acc[5][n] = MF(a10, bf0[n], acc[5][n]);
      acc[5][n] = MF(a11, bf1[n], acc[5][n]);
    }
    __builtin_amdgcn_s_setprio(0);
    BARX();

    // ---------- phase 3: read A m6,m7; counted vmcnt (tile t+1 landed); MFMA m6,m7
    a00 = RDA(buf, 6, 0); a01 = RDA(buf, 6, 1);
    a10 = RDA(buf, 7, 0); a11 = RDA(buf, 7, 1);
    if (st2) { VMW4(); } else if (st1) { VMW0(); }
    BARX(); LGKM0();
    __builtin_amdgcn_s_setprio(1);
    #pragma unroll
    for (int n = 0; n < 4; ++n) {
      acc[6][n] = MF(a00, bf0[n], acc[6][n]);
      acc[6][n] = MF(a01, bf1[n], acc[6][n]);
      acc[7][n] = MF(a10, bf0[n], acc[7][n]);
      acc[7][n] = MF(a11, bf1[n], acc[7][n]);
    }
    __builtin_amdgcn_s_setprio(0);
    BARX();
  }

  // ---- epilogue
  const int row0 = cm * 256 + wr * 128 + hi * 4;
  const int col0 = bn * 256 + wc * 64 + fr;
  #pragma unroll
  for (int m = 0; m < 8; ++m)
    #pragma unroll
    for (int n = 0; n < 4; ++n)
      #pragma unroll
      for (int j = 0; j < 4; ++j) {
        float val = acc[m][n][j] * alpha;
        size_t idx = (size_t)(row0 + m * 16 + j) * ldc + (col0 + n * 16);
        if constexpr (sizeof(OutT) == 2) Cg[idx] = f2bf(val);
        else Cg[idx] = val;
      }
#undef RDA
#undef RDB
}

// ---------------------------------------------------------------- 2-phase 128^2 GEMM (PV only)
// MODE 2: causal PV, K clipped to (bm+1)*BM, longest-blocks-first.
#define BM 128
#define BN 128
#define BK 32

template<typename OutT, int MODE>
__global__ __launch_bounds__(256) void gemm_bt(
    const u16* __restrict__ A, const u16* __restrict__ B, OutT* __restrict__ C,
    int K, int lda, int ldb, int ldc,
    size_t sA, size_t sB, size_t sC, float alpha) {
  int bn, bm, bz;
  int l = blockIdx.x;
  bm = 15 - (l >> 5);                  // longest kEnd first
  int rest = l & 31;
  bz = rest >> 3;
  bn = rest & 7;
  int kEnd = (K < (bm + 1) * BM) ? K : (bm + 1) * BM;
  const u16* Ag = A + sA * bz + (size_t)bm * BM * lda;
  const u16* Bg = B + sB * bz + (size_t)bn * BN * ldb;
  OutT* Cg = C + sC * bz;

  __shared__ __align__(16) u16 As[2][BM * BK];
  __shared__ __align__(16) u16 Bs[2][BN * BK];

  const int tid = threadIdx.x;
  const int lane = tid & 63, wave = tid >> 6;
  const int wr = wave >> 1, wc = wave & 1;

  const int ch0 = wave, ch1 = wave + 4;
  const int e0 = ch0 * 512 + lane * 8, e1 = ch1 * 512 + lane * 8;
  const int r0 = e0 >> 5, c0 = e0 & 31, r1 = e1 >> 5, c1 = e1 & 31;
  const u16* a0 = Ag + (size_t)r0 * lda + c0;
  const u16* a1 = Ag + (size_t)r1 * lda + c1;
  const u16* b0 = Bg + (size_t)r0 * ldb + c0;
  const u16* b1 = Bg + (size_t)r1 * ldb + c1;

  f32x4 acc[4][4] = {};

  const int fr = lane & 15, kq = (lane >> 4) * 8;
  const int nt = kEnd / BK;

  gload16(a0, &As[0][ch0 * 512]);
  gload16(a1, &As[0][ch1 * 512]);
  gload16(b0, &Bs[0][ch0 * 512]);
  gload16(b1, &Bs[0][ch1 * 512]);
  __syncthreads();

  for (int t = 0; t < nt; ++t) {
    const int cur = t & 1;
    if (t + 1 < nt) {
      const int k0 = (t + 1) * BK;
      gload16(a0 + k0, &As[cur ^ 1][ch0 * 512]);
      gload16(a1 + k0, &As[cur ^ 1][ch1 * 512]);
      gload16(b0 + k0, &Bs[cur ^ 1][ch0 * 512]);
      gload16(b1 + k0, &Bs[cur ^ 1][ch1 * 512]);
    }
    bf16x8 af[4], bfv[4];
    #pragma unroll
    for (int m = 0; m < 4; ++m)
      af[m] = *reinterpret_cast<const bf16x8*>(&As[cur][(wr * 64 + m * 16 + fr) * BK + kq]);
    #pragma unroll
    for (int n = 0; n < 4; ++n)
      bfv[n] = *reinterpret_cast<const bf16x8*>(&Bs[cur][(wc * 64 + n * 16 + fr) * BK + kq]);
    #pragma unroll
    for (int m = 0; m < 4; ++m)
      #pragma unroll
      for (int n = 0; n < 4; ++n)
        acc[m][n] = MF(af[m], bfv[n], acc[m][n]);
    __syncthreads();
  }

  const int row0 = bm * BM + wr * 64 + (lane >> 4) * 4;
  const int col0 = bn * BN + wc * 64 + fr;
  #pragma unroll
  for (int m = 0; m < 4; ++m)
    #pragma unroll
    for (int n = 0; n < 4; ++n) {
      #pragma unroll
      for (int j = 0; j < 4; ++j) {
        float val = acc[m][n][j] * alpha;
        size_t idx = (size_t)(row0 + m * 16 + j) * ldc + (col0 + n * 16);
        if constexpr (sizeof(OutT) == 2) Cg[idx] = f2bf(val);
        else Cg[idx] = val;
      }
    }
}

// ---------------------------------------------------------------- causal softmax (in-place)
__global__ __launch_bounds__(256) void softmax_causal(float* __restrict__ sc) {
  int r = blockIdx.x;          // 0..8191
  int s = r & 2047;
  float* row = sc + (size_t)r * 2048;
  int tid = threadIdx.x;
  int t0 = tid * 8;
  f4v x0 = {-1e30f, -1e30f, -1e30f, -1e30f};
  f4v x1 = {-1e30f, -1e30f, -1e30f, -1e30f};
  if (t0 <= s)     x0 = reinterpret_cast<const f4v*>(row)[tid * 2];
  if (t0 + 4 <= s) x1 = reinterpret_cast<const f4v*>(row)[tid * 2 + 1];
  float v[8] = {x0[0], x0[1], x0[2], x0[3], x1[0], x1[1], x1[2], x1[3]};
  float mx = -1e30f;
  #pragma unroll
  for (int j = 0; j < 8; ++j) {
    v[j] = ((t0 + j) <= s) ? v[j] : -1e30f;
    mx = fmaxf(mx, v[j]);
  }
  #pragma unroll
  for (int o = 32; o; o >>= 1) mx = fmaxf(mx, __shfl_xor(mx, o, 64));
  __shared__ float red[8];
  if ((tid & 63) == 0) red[tid >> 6] = mx;
  __syncthreads();
  mx = fmaxf(fmaxf(red[0], red[1]), fmaxf(red[2], red[3]));
  float p[8];
  float sum = 0.f;
  #pragma unroll
  for (int j = 0; j < 8; ++j) {
    p[j] = ((t0 + j) <= s) ? __expf(v[j] - mx) : 0.f;
    sum += p[j];
  }
  #pragma unroll
  for (int o = 32; o; o >>= 1) sum += __shfl_xor(sum, o, 64);
  if ((tid & 63) == 0) red[4 + (tid >> 6)] = sum;
  __syncthreads();
  sum = red[4] + red[5] + red[6] + red[7];
  float inv = 1.0f / sum;
  u16x8 o8;
  #pragma unroll
  for (int j = 0; j < 8; ++j) o8[j] = f2bf(p[j] * inv);
  if (t0 <= (s | 127))   // PV reads cols < (bm+1)*128 only
    reinterpret_cast<u16x8*>(row)[tid] = o8;
}

// ---------------------------------------------------------------- launcher
extern "C" void kernel_launch(void* const* d_in, const int* in_sizes, int n_in,
                              void* d_out, int out_size, void* d_ws, size_t ws_size,
                              hipStream_t stream) {
  const float* q  = (const float*)d_in[0];
  const float* k  = (const float*)d_in[1];
  const float* v  = (const float*)d_in[2];
  // d_in[3] = attn_mask (causal tril) — handled analytically
  const float* Wq = (const float*)d_in[4];
  const float* Wk = (const float*)d_in[5];
  const float* Wv = (const float*)d_in[6];
  float* out = (float*)d_out;
  char* ws = (char*)d_ws;

  const size_t MB = 1024ull * 1024ull;
  u16* qb  = (u16*)(ws + 0 * MB);    // 48MB stacked x/k/v bf16 (dead after proj)
  u16* wqb = (u16*)(ws + 48 * MB);   // 6MB  weights bf16 (dead after proj)
  u16* Vp  = (u16*)(ws + 54 * MB);   // 16MB (dead after transpose)
  u16* Vt  = (u16*)(ws + 70 * MB);   // 16MB
  u16* Kp  = (u16*)(ws + 86 * MB);   // 16MB
  u16* Qp  = (u16*)(ws + 102 * MB);  // 16MB  -> peak 118MB
  float* sc = (float*)ws;            // 64MB, overlays dead casts+weights+Vp

  // 1. casts
  cast3_f32_bf16<<<dim3(4096, 1, 3), 256, 0, stream>>>(q, k, v, qb, 8ull * MB);
  cast3_f32_bf16<<<dim3(512, 1, 3), 256, 0, stream>>>(Wq, Wk, Wv, wqb, 1ull * MB);

  // 2. stacked projections, 256^2 8-phase (384 blocks, XCD-swizzled)
  gemm256<u16, 0><<<384, 512, 0, stream>>>(
      qb, wqb, Qp, 1024, 1024, 1024, 1024,
      0, 1048576, 0, 1.0f, Kp, Vp);

  // 3. V transpose -> Vt[4][1024][2048]
  transpose_bf16k<<<dim3(16, 32, 4), 256, 0, stream>>>(Vp, Vt);

  // 4. QK^T, 256^2 8-phase, triangular-packed (144 blocks) -> scores f32
  gemm256<float, 1><<<144, 512, 0, stream>>>(
      Qp, Kp, sc, 1024, 1024, 1024, 2048,
      (size_t)2048 * 1024, (size_t)2048 * 1024, (size_t)2048 * 2048, 0.03125f,
      nullptr, nullptr);

  // 5. causal softmax, bf16 P written in place (ldp = 4096 u16)
  softmax_causal<<<8192, 256, 0, stream>>>(sc);

  // 6. PV: P[2048][2048](lda 4096) . Vt[1024][2048]^T -> out f32, longest-first
  gemm_bt<float, 2><<<512, 256, 0, stream>>>(
      (u16*)ws, Vt, out, 2048, 4096, 2048, 1024,
      (size_t)2048 * 4096, (size_t)1024 * 2048, (size_t)2048 * 1024, 1.0f);
}